// Round 1
// baseline (529.753 us; speedup 1.0000x reference)
//
#include <hip/hip_runtime.h>
#include <hip/hip_bf16.h>
#include <math.h>

#define BB 32
#define NN 512
#define NF 256
#define NHID 64
#define NHEADS_ 8
#define NO 128
#define ALPHA 0.2f
#define ACVT 0.01f

__device__ __forceinline__ float leakyf(float x, float s) { return x >= 0.f ? x : s * x; }

// C[M][N] = act(A[M][K]) * Bm[N][K]^T   (fp32, 64x64 tile, 4x4/thread)
template <bool LEAKY_A>
__global__ __launch_bounds__(256) void gemm_nt(const float* __restrict__ A,
                                               const float* __restrict__ Bm,
                                               float* __restrict__ C,
                                               int M, int N, int K) {
    __shared__ float As[16][68];
    __shared__ float Bs[16][68];
    const int m0 = blockIdx.x * 64, n0 = blockIdx.y * 64;
    const int tid = threadIdx.x;
    const int tm = tid >> 4, tn = tid & 15;
    const int lr = tid >> 2, lq = tid & 3;
    float c[4][4];
#pragma unroll
    for (int i = 0; i < 4; i++)
#pragma unroll
        for (int j = 0; j < 4; j++) c[i][j] = 0.f;

    const float* ap = A + (size_t)(m0 + lr) * K + lq * 4;
    const float* bp = Bm + (size_t)(n0 + lr) * K + lq * 4;

    for (int k0 = 0; k0 < K; k0 += 16) {
        float4 av = *(const float4*)(ap + k0);
        float4 bv = *(const float4*)(bp + k0);
        if (LEAKY_A) {
            av.x = leakyf(av.x, ACVT); av.y = leakyf(av.y, ACVT);
            av.z = leakyf(av.z, ACVT); av.w = leakyf(av.w, ACVT);
        }
        __syncthreads();
        As[lq * 4 + 0][lr] = av.x; As[lq * 4 + 1][lr] = av.y;
        As[lq * 4 + 2][lr] = av.z; As[lq * 4 + 3][lr] = av.w;
        Bs[lq * 4 + 0][lr] = bv.x; Bs[lq * 4 + 1][lr] = bv.y;
        Bs[lq * 4 + 2][lr] = bv.z; Bs[lq * 4 + 3][lr] = bv.w;
        __syncthreads();
#pragma unroll
        for (int kk = 0; kk < 16; kk++) {
            float4 a4 = *(const float4*)&As[kk][tm * 4];
            float4 b4 = *(const float4*)&Bs[kk][tn * 4];
            float a[4] = {a4.x, a4.y, a4.z, a4.w};
            float b[4] = {b4.x, b4.y, b4.z, b4.w};
#pragma unroll
            for (int i = 0; i < 4; i++)
#pragma unroll
                for (int j = 0; j < 4; j++) c[i][j] += a[i] * b[j];
        }
    }
#pragma unroll
    for (int i = 0; i < 4; i++)
#pragma unroll
        for (int j = 0; j < 4; j++)
            C[(size_t)(m0 + tm * 4 + i) * N + n0 + tn * 4 + j] = c[i][j];
}

// e1[b,h,n] = dot(H[b,n,h*64:+64], a1[h]);  e2 likewise
__global__ __launch_bounds__(256) void e1e2_k(const float* __restrict__ H,
                                              const float* __restrict__ a1,
                                              const float* __restrict__ a2,
                                              float* __restrict__ E1,
                                              float* __restrict__ E2) {
    int t = blockIdx.x * 256 + threadIdx.x;  // < 32*8*512
    int n = t & 511, h = (t >> 9) & 7, b = t >> 12;
    const float* hp = H + ((size_t)b * NN + n) * 512 + h * 64;
    const float* p1 = a1 + h * 64;
    const float* p2 = a2 + h * 64;
    float s1 = 0.f, s2 = 0.f;
#pragma unroll
    for (int d = 0; d < 64; d += 4) {
        float4 hv = *(const float4*)(hp + d);
        float4 v1 = *(const float4*)(p1 + d);
        float4 v2 = *(const float4*)(p2 + d);
        s1 += hv.x * v1.x + hv.y * v1.y + hv.z * v1.z + hv.w * v1.w;
        s2 += hv.x * v2.x + hv.y * v2.y + hv.z * v2.z + hv.w * v2.w;
    }
    E1[(size_t)(b * 8 + h) * NN + n] = s1;
    E2[(size_t)(b * 8 + h) * NN + n] = s2;
}

// per (b,h): O[j, h*64+d] = sum_k softmax_k(leaky(e1[k]+e2[j])) * H[k,d]
__global__ __launch_bounds__(256) void attn_mh(const float* __restrict__ H,
                                               const float* __restrict__ E1,
                                               const float* __restrict__ E2,
                                               float* __restrict__ O) {
    __shared__ float Hs[NN * NHID];      // 128 KB, [k][d]
    __shared__ float e1s[NN];            // 2 KB
    __shared__ float attw[4][2][516];    // 16.5 KB, padded k + (k>>7)
    const int bh = blockIdx.x;
    const int b = bh >> 3, h = bh & 7;
    const int tid = threadIdx.x;

    {
        const int q = tid & 15;
        const size_t base = ((size_t)b * NN) * 512 + h * 64 + q * 4;
        for (int rr = tid >> 4; rr < NN; rr += 16) {
            float4 v = *(const float4*)(H + base + (size_t)rr * 512);
            *(float4*)&Hs[rr * 64 + q * 4] = v;
        }
    }
    for (int i = tid; i < NN; i += 256) e1s[i] = E1[(size_t)bh * NN + i];
    __syncthreads();

    const int wave = tid >> 6, lane = tid & 63;
    const int d4 = lane & 15, kc = lane >> 4;
    const float* e2g = E2 + (size_t)bh * NN;

    for (int j0 = wave * 128; j0 < wave * 128 + 128; j0 += 2) {
        float e20 = e2g[j0], e21 = e2g[j0 + 1];
        float p0[8], p1[8];
        float m0 = -1e30f, m1 = -1e30f;
#pragma unroll
        for (int i = 0; i < 8; i++) {
            float ev = e1s[lane + 64 * i];
            float s0 = ev + e20; s0 = s0 >= 0.f ? s0 : ALPHA * s0;
            float s1 = ev + e21; s1 = s1 >= 0.f ? s1 : ALPHA * s1;
            p0[i] = s0; p1[i] = s1;
            m0 = fmaxf(m0, s0); m1 = fmaxf(m1, s1);
        }
#pragma unroll
        for (int off = 32; off >= 1; off >>= 1) {
            m0 = fmaxf(m0, __shfl_xor(m0, off, 64));
            m1 = fmaxf(m1, __shfl_xor(m1, off, 64));
        }
        float z0 = 0.f, z1 = 0.f;
#pragma unroll
        for (int i = 0; i < 8; i++) {
            p0[i] = __expf(p0[i] - m0); z0 += p0[i];
            p1[i] = __expf(p1[i] - m1); z1 += p1[i];
        }
#pragma unroll
        for (int off = 32; off >= 1; off >>= 1) {
            z0 += __shfl_xor(z0, off, 64);
            z1 += __shfl_xor(z1, off, 64);
        }
        float i0 = 1.f / z0, i1 = 1.f / z1;
#pragma unroll
        for (int i = 0; i < 8; i++) {
            int k = lane + 64 * i;
            int kx = k + (k >> 7);
            attw[wave][0][kx] = p0[i] * i0;
            attw[wave][1][kx] = p1[i] * i1;
        }
        float4 acc0 = make_float4(0, 0, 0, 0), acc1 = make_float4(0, 0, 0, 0);
        const float* hb = &Hs[kc * 128 * 64 + d4 * 4];
        const float* a0p = &attw[wave][0][kc * 129];
        const float* a1p = &attw[wave][1][kc * 129];
#pragma unroll 8
        for (int kk = 0; kk < 128; kk++) {
            float4 hv = *(const float4*)(hb + kk * 64);
            float w0 = a0p[kk], w1 = a1p[kk];
            acc0.x += w0 * hv.x; acc0.y += w0 * hv.y;
            acc0.z += w0 * hv.z; acc0.w += w0 * hv.w;
            acc1.x += w1 * hv.x; acc1.y += w1 * hv.y;
            acc1.z += w1 * hv.z; acc1.w += w1 * hv.w;
        }
#pragma unroll
        for (int off = 16; off <= 32; off <<= 1) {
            acc0.x += __shfl_xor(acc0.x, off, 64); acc0.y += __shfl_xor(acc0.y, off, 64);
            acc0.z += __shfl_xor(acc0.z, off, 64); acc0.w += __shfl_xor(acc0.w, off, 64);
            acc1.x += __shfl_xor(acc1.x, off, 64); acc1.y += __shfl_xor(acc1.y, off, 64);
            acc1.z += __shfl_xor(acc1.z, off, 64); acc1.w += __shfl_xor(acc1.w, off, 64);
        }
        if (kc == 0) {
            *(float4*)(O + ((size_t)b * NN + j0) * 512 + h * 64 + d4 * 4) = acc0;
            *(float4*)(O + ((size_t)b * NN + j0 + 1) * 512 + h * 64 + d4 * 4) = acc1;
        }
    }
}

// f1/f2[b,n] = dot(h2[b,n,:], a1_out / a2_out)
__global__ __launch_bounds__(256) void f1f2_k(const float* __restrict__ H2,
                                              const float* __restrict__ a1o,
                                              const float* __restrict__ a2o,
                                              float* __restrict__ F1,
                                              float* __restrict__ F2) {
    int t = blockIdx.x * 256 + threadIdx.x;  // < 32*512
    const float* hp = H2 + (size_t)t * NO;
    float s1 = 0.f, s2 = 0.f;
#pragma unroll
    for (int d = 0; d < NO; d += 4) {
        float4 hv = *(const float4*)(hp + d);
        float4 v1 = *(const float4*)(a1o + d);
        float4 v2 = *(const float4*)(a2o + d);
        s1 += hv.x * v1.x + hv.y * v1.y + hv.z * v1.z + hv.w * v1.w;
        s2 += hv.x * v2.x + hv.y * v2.y + hv.z * v2.z + hv.w * v2.w;
    }
    F1[t] = s1;
    F2[t] = s2;
}

// per b: w[k] = mean_j softmax_k(leaky(f1[k]+f2[j])); v = sum_k w[k]*h2[k,:];
// out = normalize(v @ Wl^T + bl)
__global__ __launch_bounds__(256) void final_k(const float* __restrict__ H2,
                                               const float* __restrict__ F1,
                                               const float* __restrict__ F2,
                                               const float* __restrict__ Wl,
                                               const float* __restrict__ bl,
                                               float* __restrict__ out) {
    __shared__ float f1s[NN], f2s[NN];
    __shared__ float wws[4][NN];
    __shared__ float tmp[NO];
    __shared__ float fo_s[NO];
    __shared__ float red0;
    const int b = blockIdx.x, tid = threadIdx.x;
    const int wave = tid >> 6, lane = tid & 63;
    for (int i = tid; i < NN; i += 256) {
        f1s[i] = F1[(size_t)b * NN + i];
        f2s[i] = F2[(size_t)b * NN + i];
    }
#pragma unroll
    for (int i = 0; i < 8; i++) wws[wave][lane + 64 * i] = 0.f;
    __syncthreads();

    for (int j = wave; j < NN; j += 4) {
        float f2j = f2s[j];
        float p[8];
        float m = -1e30f;
#pragma unroll
        for (int i = 0; i < 8; i++) {
            float s = f1s[lane + 64 * i] + f2j;
            s = s >= 0.f ? s : ALPHA * s;
            p[i] = s;
            m = fmaxf(m, s);
        }
#pragma unroll
        for (int off = 32; off >= 1; off >>= 1) m = fmaxf(m, __shfl_xor(m, off, 64));
        float z = 0.f;
#pragma unroll
        for (int i = 0; i < 8; i++) { p[i] = __expf(p[i] - m); z += p[i]; }
#pragma unroll
        for (int off = 32; off >= 1; off >>= 1) z += __shfl_xor(z, off, 64);
        float inv = 1.f / z;
#pragma unroll
        for (int i = 0; i < 8; i++) wws[wave][lane + 64 * i] += p[i] * inv;
    }
    __syncthreads();
    for (int i = tid; i < NN; i += 256) {
        float w = (wws[0][i] + wws[1][i] + wws[2][i] + wws[3][i]) * (1.f / 512.f);
        wws[0][i] = w;
    }
    __syncthreads();
    {
        int d = tid & 127, half = tid >> 7;
        const float* h2p = H2 + ((size_t)b * NN + half * 256) * NO + d;
        float a0 = 0.f, a1v = 0.f, a2v = 0.f, a3 = 0.f;
        for (int k = 0; k < 256; k += 4) {
            a0 += wws[0][half * 256 + k + 0] * h2p[(size_t)(k + 0) * NO];
            a1v += wws[0][half * 256 + k + 1] * h2p[(size_t)(k + 1) * NO];
            a2v += wws[0][half * 256 + k + 2] * h2p[(size_t)(k + 2) * NO];
            a3 += wws[0][half * 256 + k + 3] * h2p[(size_t)(k + 3) * NO];
        }
        f1s[tid] = a0 + a1v + a2v + a3;  // reuse f1s as scratch
    }
    __syncthreads();
    if (tid < NO) tmp[tid] = f1s[tid] + f1s[tid + 128];
    __syncthreads();
    if (tid < NO) {
        float fo = bl[tid];
        const float* wl = Wl + (size_t)tid * NO;
#pragma unroll 4
        for (int d = 0; d < NO; d += 4) {
            fo += tmp[d] * wl[d] + tmp[d + 1] * wl[d + 1] + tmp[d + 2] * wl[d + 2] +
                  tmp[d + 3] * wl[d + 3];
        }
        fo_s[tid] = fo;
    }
    __syncthreads();
    if (tid < 64) {
        float s = fo_s[tid] * fo_s[tid] + fo_s[tid + 64] * fo_s[tid + 64];
#pragma unroll
        for (int off = 32; off >= 1; off >>= 1) s += __shfl_xor(s, off, 64);
        if (tid == 0) red0 = s;
    }
    __syncthreads();
    float inv = 1.f / fmaxf(sqrtf(red0), 1e-12f);
    if (tid < NO) out[(size_t)b * NO + tid] = fo_s[tid] * inv;
}

extern "C" void kernel_launch(void* const* d_in, const int* in_sizes, int n_in,
                              void* d_out, int out_size, void* d_ws, size_t ws_size,
                              hipStream_t stream) {
    const float* X = (const float*)d_in[0];    // [32,512,256]
    const float* Wt = (const float*)d_in[1];   // [8,64,256] -> [512,256]
    const float* a1 = (const float*)d_in[2];   // [8,64]
    const float* a2 = (const float*)d_in[3];   // [8,64]
    const float* Wo = (const float*)d_in[4];   // [128,512]
    const float* a1o = (const float*)d_in[5];  // [128]
    const float* a2o = (const float*)d_in[6];  // [128]
    const float* Wl = (const float*)d_in[7];   // [128,128]
    const float* bl = (const float*)d_in[8];   // [128]
    float* out = (float*)d_out;                // [32,128]
    float* ws = (float*)d_ws;

    float* H = ws;                             // 32*512*512
    float* E1 = H + (size_t)32 * 512 * 512;    // 32*8*512
    float* E2 = E1 + (size_t)32 * 8 * 512;     // 32*8*512
    float* O = E2 + (size_t)32 * 8 * 512;      // 32*512*512
    float* H2 = O + (size_t)32 * 512 * 512;    // 32*512*128
    float* F1 = H2 + (size_t)32 * 512 * 128;   // 32*512
    float* F2 = F1 + (size_t)32 * 512;         // 32*512

    gemm_nt<false><<<dim3(256, 8), 256, 0, stream>>>(X, Wt, H, 16384, 512, 256);
    e1e2_k<<<512, 256, 0, stream>>>(H, a1, a2, E1, E2);
    attn_mh<<<256, 256, 0, stream>>>(H, E1, E2, O);
    gemm_nt<true><<<dim3(256, 2), 256, 0, stream>>>(O, Wo, H2, 16384, 128, 512);
    f1f2_k<<<64, 256, 0, stream>>>(H2, a1o, a2o, F1, F2);
    final_k<<<32, 256, 0, stream>>>(H2, F1, F2, Wl, bl, out);
}

// Round 2
// 301.993 us; speedup vs baseline: 1.7542x; 1.7542x over previous
//
#include <hip/hip_runtime.h>
#include <hip/hip_bf16.h>
#include <math.h>

#define BB 32
#define NN 512
#define NF 256
#define NHID 64
#define NHEADS_ 8
#define NO 128
#define ALPHA 0.2f
#define ACVT 0.01f

typedef __attribute__((ext_vector_type(8))) __bf16 bf16x8;
typedef __attribute__((ext_vector_type(4))) float f32x4;

__device__ __forceinline__ float leakyf(float x, float s) { return x >= 0.f ? x : s * x; }

// C[M][N] = act(A[M][K]) * Bm[N][K]^T   (fp32, 64x64 tile, 4x4/thread)
template <bool LEAKY_A>
__global__ __launch_bounds__(256) void gemm_nt(const float* __restrict__ A,
                                               const float* __restrict__ Bm,
                                               float* __restrict__ C,
                                               int M, int N, int K) {
    __shared__ float As[16][68];
    __shared__ float Bs[16][68];
    const int m0 = blockIdx.x * 64, n0 = blockIdx.y * 64;
    const int tid = threadIdx.x;
    const int tm = tid >> 4, tn = tid & 15;
    const int lr = tid >> 2, lq = tid & 3;
    float c[4][4];
#pragma unroll
    for (int i = 0; i < 4; i++)
#pragma unroll
        for (int j = 0; j < 4; j++) c[i][j] = 0.f;

    const float* ap = A + (size_t)(m0 + lr) * K + lq * 4;
    const float* bp = Bm + (size_t)(n0 + lr) * K + lq * 4;

    for (int k0 = 0; k0 < K; k0 += 16) {
        float4 av = *(const float4*)(ap + k0);
        float4 bv = *(const float4*)(bp + k0);
        if (LEAKY_A) {
            av.x = leakyf(av.x, ACVT); av.y = leakyf(av.y, ACVT);
            av.z = leakyf(av.z, ACVT); av.w = leakyf(av.w, ACVT);
        }
        __syncthreads();
        As[lq * 4 + 0][lr] = av.x; As[lq * 4 + 1][lr] = av.y;
        As[lq * 4 + 2][lr] = av.z; As[lq * 4 + 3][lr] = av.w;
        Bs[lq * 4 + 0][lr] = bv.x; Bs[lq * 4 + 1][lr] = bv.y;
        Bs[lq * 4 + 2][lr] = bv.z; Bs[lq * 4 + 3][lr] = bv.w;
        __syncthreads();
#pragma unroll
        for (int kk = 0; kk < 16; kk++) {
            float4 a4 = *(const float4*)&As[kk][tm * 4];
            float4 b4 = *(const float4*)&Bs[kk][tn * 4];
            float a[4] = {a4.x, a4.y, a4.z, a4.w};
            float b[4] = {b4.x, b4.y, b4.z, b4.w};
#pragma unroll
            for (int i = 0; i < 4; i++)
#pragma unroll
                for (int j = 0; j < 4; j++) c[i][j] += a[i] * b[j];
        }
    }
#pragma unroll
    for (int i = 0; i < 4; i++)
#pragma unroll
        for (int j = 0; j < 4; j++)
            C[(size_t)(m0 + tm * 4 + i) * N + n0 + tn * 4 + j] = c[i][j];
}

// e1[b,h,n] = dot(H[b,n,h*64:+64], a1[h]);  e2 likewise
__global__ __launch_bounds__(256) void e1e2_k(const float* __restrict__ H,
                                              const float* __restrict__ a1,
                                              const float* __restrict__ a2,
                                              float* __restrict__ E1,
                                              float* __restrict__ E2) {
    int t = blockIdx.x * 256 + threadIdx.x;  // < 32*8*512
    int n = t & 511, h = (t >> 9) & 7, b = t >> 12;
    const float* hp = H + ((size_t)b * NN + n) * 512 + h * 64;
    const float* p1 = a1 + h * 64;
    const float* p2 = a2 + h * 64;
    float s1 = 0.f, s2 = 0.f;
#pragma unroll
    for (int d = 0; d < 64; d += 4) {
        float4 hv = *(const float4*)(hp + d);
        float4 v1 = *(const float4*)(p1 + d);
        float4 v2 = *(const float4*)(p2 + d);
        s1 += hv.x * v1.x + hv.y * v1.y + hv.z * v1.z + hv.w * v1.w;
        s2 += hv.x * v2.x + hv.y * v2.y + hv.z * v2.z + hv.w * v2.w;
    }
    E1[(size_t)(b * 8 + h) * NN + n] = s1;
    E2[(size_t)(b * 8 + h) * NN + n] = s2;
}

// per (b,h): O[j, h*64+d] = sum_k softmax_k(leaky(e1[k]+e2[j])) * H[k,d]
// MFMA version: grid = 512 blocks = (bh, halfM). 4 waves x 64 rows each.
// Unnormalized p accumulated via mfma_16x16x32_bf16; rows scaled by 1/z at end.
__global__ __launch_bounds__(256) void attn_mfma(const float* __restrict__ H,
                                                 const float* __restrict__ E1,
                                                 const float* __restrict__ E2,
                                                 float* __restrict__ O) {
    __shared__ short Ht[64 * 512];   // 64 KB: bf16 H^T [d][k], XOR-swizzled
    __shared__ float e1s[512];
    __shared__ float red[4][64];     // e1max scratch, then per-wave 1/z
    __shared__ float e1maxS;

    const int bid = blockIdx.x;
    const int bh = bid >> 1, half = bid & 1;
    const int b = bh >> 3, h = bh & 7;
    const int tid = threadIdx.x;
    const int w = tid >> 6, lane = tid & 63;
    const int r = lane & 15, g = lane >> 4;

    // ---- stage H^T as bf16 into LDS (lane = d, 8 k's per iter) ----
    {
        const float* hg = H + (size_t)b * 512 * 512 + h * 64 + lane;
        for (int i = 0; i < 16; ++i) {
            int k0 = (i * 4 + w) * 8;
            bf16x8 sv;
#pragma unroll
            for (int q = 0; q < 8; ++q) sv[q] = (__bf16)hg[(size_t)(k0 + q) * 512];
            int off = (lane << 10) + (k0 << 1);
            off ^= (lane & 7) << 4;
            *(bf16x8*)((char*)Ht + off) = sv;
        }
    }
    for (int i = tid; i < 512; i += 256) e1s[i] = E1[(size_t)bh * 512 + i];
    __syncthreads();

    // ---- e1max (leaky monotonic => row max = leaky(e1max + e2[j])) ----
    ((float*)red)[tid] = fmaxf(e1s[tid], e1s[tid + 256]);
    __syncthreads();
    if (tid < 64) {
        const float* rp = (const float*)red;
        float m = fmaxf(fmaxf(rp[tid], rp[tid + 64]), fmaxf(rp[tid + 128], rp[tid + 192]));
#pragma unroll
        for (int off = 32; off >= 1; off >>= 1) m = fmaxf(m, __shfl_xor(m, off, 64));
        if (tid == 0) e1maxS = m;
    }
    __syncthreads();
    const float e1max = e1maxS;

    // ---- per-lane row constants (4 M-tiles of 16 rows; lane owns row r) ----
    float ee2[4], mm[4];
    const float* e2g = E2 + (size_t)bh * 512 + half * 256 + w * 64;
#pragma unroll
    for (int mt = 0; mt < 4; ++mt) {
        float v = e2g[mt * 16 + r];
        ee2[mt] = v;
        float s = e1max + v;
        mm[mt] = fmaxf(s, ALPHA * s);
    }

    f32x4 acc[4][4];
#pragma unroll
    for (int mt = 0; mt < 4; ++mt)
#pragma unroll
        for (int nt = 0; nt < 4; ++nt) {
            acc[mt][nt][0] = 0.f; acc[mt][nt][1] = 0.f;
            acc[mt][nt][2] = 0.f; acc[mt][nt][3] = 0.f;
        }
    float zac[4] = {0.f, 0.f, 0.f, 0.f};

    // ---- K loop: 16 chunks of 32 ----
    for (int c = 0; c < 16; ++c) {
        const float* ep = e1s + c * 32 + g * 8;
        float4 ea = *(const float4*)(ep);
        float4 eb = *(const float4*)(ep + 4);
        float e1c[8] = {ea.x, ea.y, ea.z, ea.w, eb.x, eb.y, eb.z, eb.w};

        bf16x8 bfr[4];
#pragma unroll
        for (int nt = 0; nt < 4; ++nt) {
            int n = nt * 16 + r;
            int off = (n << 10) + ((c * 32 + g * 8) << 1);
            off ^= (n & 7) << 4;
            bfr[nt] = *(const bf16x8*)((const char*)Ht + off);
        }
#pragma unroll
        for (int mt = 0; mt < 4; ++mt) {
            bf16x8 af;
            float zp = 0.f;
#pragma unroll
            for (int q = 0; q < 8; ++q) {
                float s = e1c[q] + ee2[mt];
                s = fmaxf(s, ALPHA * s);       // leaky (slope<1)
                float p = __expf(s - mm[mt]);  // <= 1
                zp += p;
                af[q] = (__bf16)p;
            }
            zac[mt] += zp;
#pragma unroll
            for (int nt = 0; nt < 4; ++nt)
                acc[mt][nt] =
                    __builtin_amdgcn_mfma_f32_16x16x32_bf16(af, bfr[nt], acc[mt][nt], 0, 0, 0);
        }
    }

    // ---- z reduce across k-groups, stash 1/z per row ----
#pragma unroll
    for (int mt = 0; mt < 4; ++mt) {
        float z = zac[mt];
        z += __shfl_xor(z, 16, 64);
        z += __shfl_xor(z, 32, 64);
        if (g == 0) red[w][mt * 16 + r] = 1.f / z;
    }
    // same-wave LDS producer/consumer: no block barrier needed

    // ---- epilogue: C layout col=lane&15, row=(lane>>4)*4+reg ----
    float* ob = O + ((size_t)b * 512 + half * 256 + w * 64) * 512 + h * 64;
#pragma unroll
    for (int mt = 0; mt < 4; ++mt) {
#pragma unroll
        for (int reg = 0; reg < 4; ++reg) {
            int row = mt * 16 + g * 4 + reg;
            float zi = red[w][row];
#pragma unroll
            for (int nt = 0; nt < 4; ++nt)
                ob[(size_t)row * 512 + nt * 16 + r] = acc[mt][nt][reg] * zi;
        }
    }
}

// f1/f2[b,n] = dot(h2[b,n,:], a1_out / a2_out)
__global__ __launch_bounds__(256) void f1f2_k(const float* __restrict__ H2,
                                              const float* __restrict__ a1o,
                                              const float* __restrict__ a2o,
                                              float* __restrict__ F1,
                                              float* __restrict__ F2) {
    int t = blockIdx.x * 256 + threadIdx.x;  // < 32*512
    const float* hp = H2 + (size_t)t * NO;
    float s1 = 0.f, s2 = 0.f;
#pragma unroll
    for (int d = 0; d < NO; d += 4) {
        float4 hv = *(const float4*)(hp + d);
        float4 v1 = *(const float4*)(a1o + d);
        float4 v2 = *(const float4*)(a2o + d);
        s1 += hv.x * v1.x + hv.y * v1.y + hv.z * v1.z + hv.w * v1.w;
        s2 += hv.x * v2.x + hv.y * v2.y + hv.z * v2.z + hv.w * v2.w;
    }
    F1[t] = s1;
    F2[t] = s2;
}

// per b: w[k] = mean_j softmax_k(leaky(f1[k]+f2[j])); v = sum_k w[k]*h2[k,:];
// out = normalize(v @ Wl^T + bl)
__global__ __launch_bounds__(256) void final_k(const float* __restrict__ H2,
                                               const float* __restrict__ F1,
                                               const float* __restrict__ F2,
                                               const float* __restrict__ Wl,
                                               const float* __restrict__ bl,
                                               float* __restrict__ out) {
    __shared__ float f1s[NN], f2s[NN];
    __shared__ float wws[4][NN];
    __shared__ float tmp[NO];
    __shared__ float fo_s[NO];
    __shared__ float red0;
    const int b = blockIdx.x, tid = threadIdx.x;
    const int wave = tid >> 6, lane = tid & 63;
    for (int i = tid; i < NN; i += 256) {
        f1s[i] = F1[(size_t)b * NN + i];
        f2s[i] = F2[(size_t)b * NN + i];
    }
#pragma unroll
    for (int i = 0; i < 8; i++) wws[wave][lane + 64 * i] = 0.f;
    __syncthreads();

    for (int j = wave; j < NN; j += 4) {
        float f2j = f2s[j];
        float p[8];
        float m = -1e30f;
#pragma unroll
        for (int i = 0; i < 8; i++) {
            float s = f1s[lane + 64 * i] + f2j;
            s = s >= 0.f ? s : ALPHA * s;
            p[i] = s;
            m = fmaxf(m, s);
        }
#pragma unroll
        for (int off = 32; off >= 1; off >>= 1) m = fmaxf(m, __shfl_xor(m, off, 64));
        float z = 0.f;
#pragma unroll
        for (int i = 0; i < 8; i++) { p[i] = __expf(p[i] - m); z += p[i]; }
#pragma unroll
        for (int off = 32; off >= 1; off >>= 1) z += __shfl_xor(z, off, 64);
        float inv = 1.f / z;
#pragma unroll
        for (int i = 0; i < 8; i++) wws[wave][lane + 64 * i] += p[i] * inv;
    }
    __syncthreads();
    for (int i = tid; i < NN; i += 256) {
        float w = (wws[0][i] + wws[1][i] + wws[2][i] + wws[3][i]) * (1.f / 512.f);
        wws[0][i] = w;
    }
    __syncthreads();
    {
        int d = tid & 127, half = tid >> 7;
        const float* h2p = H2 + ((size_t)b * NN + half * 256) * NO + d;
        float a0 = 0.f, a1v = 0.f, a2v = 0.f, a3 = 0.f;
        for (int k = 0; k < 256; k += 4) {
            a0 += wws[0][half * 256 + k + 0] * h2p[(size_t)(k + 0) * NO];
            a1v += wws[0][half * 256 + k + 1] * h2p[(size_t)(k + 1) * NO];
            a2v += wws[0][half * 256 + k + 2] * h2p[(size_t)(k + 2) * NO];
            a3 += wws[0][half * 256 + k + 3] * h2p[(size_t)(k + 3) * NO];
        }
        f1s[tid] = a0 + a1v + a2v + a3;  // reuse f1s as scratch
    }
    __syncthreads();
    if (tid < NO) tmp[tid] = f1s[tid] + f1s[tid + 128];
    __syncthreads();
    if (tid < NO) {
        float fo = bl[tid];
        const float* wl = Wl + (size_t)tid * NO;
#pragma unroll 4
        for (int d = 0; d < NO; d += 4) {
            fo += tmp[d] * wl[d] + tmp[d + 1] * wl[d + 1] + tmp[d + 2] * wl[d + 2] +
                  tmp[d + 3] * wl[d + 3];
        }
        fo_s[tid] = fo;
    }
    __syncthreads();
    if (tid < 64) {
        float s = fo_s[tid] * fo_s[tid] + fo_s[tid + 64] * fo_s[tid + 64];
#pragma unroll
        for (int off = 32; off >= 1; off >>= 1) s += __shfl_xor(s, off, 64);
        if (tid == 0) red0 = s;
    }
    __syncthreads();
    float inv = 1.f / fmaxf(sqrtf(red0), 1e-12f);
    if (tid < NO) out[(size_t)b * NO + tid] = fo_s[tid] * inv;
}

extern "C" void kernel_launch(void* const* d_in, const int* in_sizes, int n_in,
                              void* d_out, int out_size, void* d_ws, size_t ws_size,
                              hipStream_t stream) {
    const float* X = (const float*)d_in[0];    // [32,512,256]
    const float* Wt = (const float*)d_in[1];   // [8,64,256] -> [512,256]
    const float* a1 = (const float*)d_in[2];   // [8,64]
    const float* a2 = (const float*)d_in[3];   // [8,64]
    const float* Wo = (const float*)d_in[4];   // [128,512]
    const float* a1o = (const float*)d_in[5];  // [128]
    const float* a2o = (const float*)d_in[6];  // [128]
    const float* Wl = (const float*)d_in[7];   // [128,128]
    const float* bl = (const float*)d_in[8];   // [128]
    float* out = (float*)d_out;                // [32,128]
    float* ws = (float*)d_ws;

    float* H = ws;                             // 32*512*512
    float* E1 = H + (size_t)32 * 512 * 512;    // 32*8*512
    float* E2 = E1 + (size_t)32 * 8 * 512;     // 32*8*512
    float* O = E2 + (size_t)32 * 8 * 512;      // 32*512*512
    float* H2 = O + (size_t)32 * 512 * 512;    // 32*512*128
    float* F1 = H2 + (size_t)32 * 512 * 128;   // 32*512
    float* F2 = F1 + (size_t)32 * 512;         // 32*512

    gemm_nt<false><<<dim3(256, 8), 256, 0, stream>>>(X, Wt, H, 16384, 512, 256);
    e1e2_k<<<512, 256, 0, stream>>>(H, a1, a2, E1, E2);
    attn_mfma<<<512, 256, 0, stream>>>(H, E1, E2, O);
    gemm_nt<true><<<dim3(256, 2), 256, 0, stream>>>(O, Wo, H2, 16384, 128, 512);
    f1f2_k<<<64, 256, 0, stream>>>(H2, a1o, a2o, F1, F2);
    final_k<<<32, 256, 0, stream>>>(H2, F1, F2, Wl, bl, out);
}

// Round 3
// 196.759 us; speedup vs baseline: 2.6924x; 1.5348x over previous
//
#include <hip/hip_runtime.h>
#include <hip/hip_bf16.h>
#include <math.h>

#define BB 32
#define NN 512
#define NF 256
#define NHID 64
#define NHEADS_ 8
#define NO 128
#define ALPHA 0.2f
#define ACVT 0.01f

typedef __attribute__((ext_vector_type(8))) __bf16 bf16x8;
typedef __attribute__((ext_vector_type(4))) __bf16 bf16x4;
typedef __attribute__((ext_vector_type(4))) float f32x4;

// ============================================================================
// MFMA GEMM, C = act(A) * Bm^T, fp32 in/out via bf16 hi/lo split (3 MFMAs).
// Block: 256 thr = 4 waves (2x2). Wave tile: (WMT*16) x 64. BM = WMT*32, BN=128.
// KC = 64 staged per chunk, XOR-swizzled LDS (byte ^= (row&7)<<4).
// EPI: 0 = none; 1 = e1/e2 per (row, head=64-col group); 2 = f1/f2 per row.
// ============================================================================
template <int WMT, bool LEAKY_A, int EPI>
__global__ __launch_bounds__(256) void gemm_mfma(
    const float* __restrict__ A, const float* __restrict__ Bm, float* __restrict__ C,
    int M, int N, int K,
    const float* __restrict__ av1, const float* __restrict__ av2,
    float* __restrict__ Ev1, float* __restrict__ Ev2) {
    constexpr int BM = WMT * 32;
    constexpr int PSA = BM * 128;    // bytes per A plane (row stride 128B)
    constexpr int PSB = 128 * 128;   // bytes per B plane
    __shared__ char As[2 * PSA];
    __shared__ char Bs[2 * PSB];
    __shared__ float fred[2][BM][2];  // EPI==2 only

    const int tid = threadIdx.x;
    const int w = tid >> 6, lane = tid & 63;
    const int wm = w >> 1, wn = w & 1;
    const int r = lane & 15, g = lane >> 4;
    const int m0 = blockIdx.x * BM;
    const int n0 = blockIdx.y * 128;

    f32x4 acc[WMT][4];
#pragma unroll
    for (int mt = 0; mt < WMT; ++mt)
#pragma unroll
        for (int nt = 0; nt < 4; ++nt) {
            acc[mt][nt][0] = 0.f; acc[mt][nt][1] = 0.f;
            acc[mt][nt][2] = 0.f; acc[mt][nt][3] = 0.f;
        }

    const int srow = tid >> 4;        // 0..15
    const int scol = (tid & 15) * 4;  // float col within 64-chunk

    for (int k0 = 0; k0 < K; k0 += 64) {
        __syncthreads();
        // ---- stage A (BM x 64 fp32 -> hi/lo bf16 planes) ----
#pragma unroll
        for (int i = 0; i < BM / 16; ++i) {
            int row = srow + i * 16;
            float4 v = *(const float4*)(A + (size_t)(m0 + row) * K + k0 + scol);
            if (LEAKY_A) {
                v.x = fmaxf(v.x, ACVT * v.x); v.y = fmaxf(v.y, ACVT * v.y);
                v.z = fmaxf(v.z, ACVT * v.z); v.w = fmaxf(v.w, ACVT * v.w);
            }
            float vv[4] = {v.x, v.y, v.z, v.w};
            bf16x4 hv, lv;
#pragma unroll
            for (int q = 0; q < 4; ++q) {
                __bf16 hb = (__bf16)vv[q];
                hv[q] = hb;
                lv[q] = (__bf16)(vv[q] - (float)hb);
            }
            int ob = (row * 128 + scol * 2) ^ ((row & 7) << 4);
            *(bf16x4*)(As + ob) = hv;
            *(bf16x4*)(As + PSA + ob) = lv;
        }
        // ---- stage B (128 x 64) ----
#pragma unroll
        for (int i = 0; i < 8; ++i) {
            int row = srow + i * 16;
            float4 v = *(const float4*)(Bm + (size_t)(n0 + row) * K + k0 + scol);
            float vv[4] = {v.x, v.y, v.z, v.w};
            bf16x4 hv, lv;
#pragma unroll
            for (int q = 0; q < 4; ++q) {
                __bf16 hb = (__bf16)vv[q];
                hv[q] = hb;
                lv[q] = (__bf16)(vv[q] - (float)hb);
            }
            int ob = (row * 128 + scol * 2) ^ ((row & 7) << 4);
            *(bf16x4*)(Bs + ob) = hv;
            *(bf16x4*)(Bs + PSB + ob) = lv;
        }
        __syncthreads();
        // ---- compute: 2 K-steps of 32 ----
#pragma unroll
        for (int kk = 0; kk < 64; kk += 32) {
            bf16x8 ah[WMT], alo[WMT], bh[4], blo[4];
#pragma unroll
            for (int mt = 0; mt < WMT; ++mt) {
                int row = wm * WMT * 16 + mt * 16 + r;
                int ob = (row * 128 + (kk + g * 8) * 2) ^ ((row & 7) << 4);
                ah[mt] = *(const bf16x8*)(As + ob);
                alo[mt] = *(const bf16x8*)(As + PSA + ob);
            }
#pragma unroll
            for (int nt = 0; nt < 4; ++nt) {
                int row = wn * 64 + nt * 16 + r;
                int ob = (row * 128 + (kk + g * 8) * 2) ^ ((row & 7) << 4);
                bh[nt] = *(const bf16x8*)(Bs + ob);
                blo[nt] = *(const bf16x8*)(Bs + PSB + ob);
            }
#pragma unroll
            for (int mt = 0; mt < WMT; ++mt)
#pragma unroll
                for (int nt = 0; nt < 4; ++nt) {
                    acc[mt][nt] = __builtin_amdgcn_mfma_f32_16x16x32_bf16(ah[mt], bh[nt], acc[mt][nt], 0, 0, 0);
                    acc[mt][nt] = __builtin_amdgcn_mfma_f32_16x16x32_bf16(ah[mt], blo[nt], acc[mt][nt], 0, 0, 0);
                    acc[mt][nt] = __builtin_amdgcn_mfma_f32_16x16x32_bf16(alo[mt], bh[nt], acc[mt][nt], 0, 0, 0);
                }
        }
    }

    // ---- C store (col = r, row = g*4+reg) ----
#pragma unroll
    for (int mt = 0; mt < WMT; ++mt)
#pragma unroll
        for (int reg = 0; reg < 4; ++reg) {
            int row = m0 + wm * WMT * 16 + mt * 16 + g * 4 + reg;
#pragma unroll
            for (int nt = 0; nt < 4; ++nt)
                C[(size_t)row * N + n0 + wn * 64 + nt * 16 + r] = acc[mt][nt][reg];
        }

    if (EPI == 1) {
        // e1/e2: per row, dot over this wave's 64 cols = head h
        const int h = blockIdx.y * 2 + wn;
        float w1[4], w2[4];
#pragma unroll
        for (int nt = 0; nt < 4; ++nt) {
            w1[nt] = av1[h * 64 + nt * 16 + r];
            w2[nt] = av2[h * 64 + nt * 16 + r];
        }
#pragma unroll
        for (int mt = 0; mt < WMT; ++mt)
#pragma unroll
            for (int reg = 0; reg < 4; ++reg) {
                float s1 = 0.f, s2 = 0.f;
#pragma unroll
                for (int nt = 0; nt < 4; ++nt) {
                    s1 += acc[mt][nt][reg] * w1[nt];
                    s2 += acc[mt][nt][reg] * w2[nt];
                }
#pragma unroll
                for (int off = 1; off <= 8; off <<= 1) {
                    s1 += __shfl_xor(s1, off, 64);
                    s2 += __shfl_xor(s2, off, 64);
                }
                if (r == 0) {
                    int m = m0 + wm * WMT * 16 + mt * 16 + g * 4 + reg;
                    int b = m >> 9, n = m & 511;
                    Ev1[(size_t)(b * 8 + h) * 512 + n] = s1;
                    Ev2[(size_t)(b * 8 + h) * 512 + n] = s2;
                }
            }
    }
    if (EPI == 2) {
        // f1/f2: per row, dot over all 128 cols (combine two wn halves via LDS)
        float w1[4], w2[4];
#pragma unroll
        for (int nt = 0; nt < 4; ++nt) {
            w1[nt] = av1[wn * 64 + nt * 16 + r];
            w2[nt] = av2[wn * 64 + nt * 16 + r];
        }
#pragma unroll
        for (int mt = 0; mt < WMT; ++mt)
#pragma unroll
            for (int reg = 0; reg < 4; ++reg) {
                float s1 = 0.f, s2 = 0.f;
#pragma unroll
                for (int nt = 0; nt < 4; ++nt) {
                    s1 += acc[mt][nt][reg] * w1[nt];
                    s2 += acc[mt][nt][reg] * w2[nt];
                }
#pragma unroll
                for (int off = 1; off <= 8; off <<= 1) {
                    s1 += __shfl_xor(s1, off, 64);
                    s2 += __shfl_xor(s2, off, 64);
                }
                if (r == 0) {
                    int lr = wm * WMT * 16 + mt * 16 + g * 4 + reg;
                    fred[wn][lr][0] = s1;
                    fred[wn][lr][1] = s2;
                }
            }
        __syncthreads();
        if (tid < BM) {
            int m = m0 + tid;
            int b = m >> 9, n = m & 511;
            Ev1[(size_t)b * 512 + n] = fred[0][tid][0] + fred[1][tid][0];
            Ev2[(size_t)b * 512 + n] = fred[0][tid][1] + fred[1][tid][1];
        }
    }
}

// ============================================================================
// per (b,h): O[j, h*64+d] = sum_k softmax_k(leaky(e1[k]+e2[j])) * H[k,d]
// ============================================================================
__global__ __launch_bounds__(256) void attn_mfma(const float* __restrict__ H,
                                                 const float* __restrict__ E1,
                                                 const float* __restrict__ E2,
                                                 float* __restrict__ O) {
    __shared__ short Ht[64 * 512];   // 64 KB: bf16 H^T [d][k], XOR-swizzled
    __shared__ float e1s[512];
    __shared__ float red[4][64];
    __shared__ float e1maxS;

    const int bid = blockIdx.x;
    const int bh = bid >> 1, half = bid & 1;
    const int b = bh >> 3, h = bh & 7;
    const int tid = threadIdx.x;
    const int w = tid >> 6, lane = tid & 63;
    const int r = lane & 15, g = lane >> 4;

    {
        const float* hg = H + (size_t)b * 512 * 512 + h * 64 + lane;
        for (int i = 0; i < 16; ++i) {
            int k0 = (i * 4 + w) * 8;
            bf16x8 sv;
#pragma unroll
            for (int q = 0; q < 8; ++q) sv[q] = (__bf16)hg[(size_t)(k0 + q) * 512];
            int off = (lane << 10) + (k0 << 1);
            off ^= (lane & 7) << 4;
            *(bf16x8*)((char*)Ht + off) = sv;
        }
    }
    for (int i = tid; i < 512; i += 256) e1s[i] = E1[(size_t)bh * 512 + i];
    __syncthreads();

    ((float*)red)[tid] = fmaxf(e1s[tid], e1s[tid + 256]);
    __syncthreads();
    if (tid < 64) {
        const float* rp = (const float*)red;
        float m = fmaxf(fmaxf(rp[tid], rp[tid + 64]), fmaxf(rp[tid + 128], rp[tid + 192]));
#pragma unroll
        for (int off = 32; off >= 1; off >>= 1) m = fmaxf(m, __shfl_xor(m, off, 64));
        if (tid == 0) e1maxS = m;
    }
    __syncthreads();
    const float e1max = e1maxS;

    float ee2[4], mm[4];
    const float* e2g = E2 + (size_t)bh * 512 + half * 256 + w * 64;
#pragma unroll
    for (int mt = 0; mt < 4; ++mt) {
        float v = e2g[mt * 16 + r];
        ee2[mt] = v;
        float s = e1max + v;
        mm[mt] = fmaxf(s, ALPHA * s);
    }

    f32x4 acc[4][4];
#pragma unroll
    for (int mt = 0; mt < 4; ++mt)
#pragma unroll
        for (int nt = 0; nt < 4; ++nt) {
            acc[mt][nt][0] = 0.f; acc[mt][nt][1] = 0.f;
            acc[mt][nt][2] = 0.f; acc[mt][nt][3] = 0.f;
        }
    float zac[4] = {0.f, 0.f, 0.f, 0.f};

    for (int c = 0; c < 16; ++c) {
        const float* ep = e1s + c * 32 + g * 8;
        float4 ea = *(const float4*)(ep);
        float4 eb = *(const float4*)(ep + 4);
        float e1c[8] = {ea.x, ea.y, ea.z, ea.w, eb.x, eb.y, eb.z, eb.w};

        bf16x8 bfr[4];
#pragma unroll
        for (int nt = 0; nt < 4; ++nt) {
            int n = nt * 16 + r;
            int off = (n << 10) + ((c * 32 + g * 8) << 1);
            off ^= (n & 7) << 4;
            bfr[nt] = *(const bf16x8*)((const char*)Ht + off);
        }
#pragma unroll
        for (int mt = 0; mt < 4; ++mt) {
            bf16x8 af;
            float zp = 0.f;
#pragma unroll
            for (int q = 0; q < 8; ++q) {
                float s = e1c[q] + ee2[mt];
                s = fmaxf(s, ALPHA * s);
                float p = __expf(s - mm[mt]);
                zp += p;
                af[q] = (__bf16)p;
            }
            zac[mt] += zp;
#pragma unroll
            for (int nt = 0; nt < 4; ++nt)
                acc[mt][nt] =
                    __builtin_amdgcn_mfma_f32_16x16x32_bf16(af, bfr[nt], acc[mt][nt], 0, 0, 0);
        }
    }

#pragma unroll
    for (int mt = 0; mt < 4; ++mt) {
        float z = zac[mt];
        z += __shfl_xor(z, 16, 64);
        z += __shfl_xor(z, 32, 64);
        if (g == 0) red[w][mt * 16 + r] = 1.f / z;
    }

    float* ob = O + ((size_t)b * 512 + half * 256 + w * 64) * 512 + h * 64;
#pragma unroll
    for (int mt = 0; mt < 4; ++mt) {
#pragma unroll
        for (int reg = 0; reg < 4; ++reg) {
            int row = mt * 16 + g * 4 + reg;
            float zi = red[w][row];
#pragma unroll
            for (int nt = 0; nt < 4; ++nt)
                ob[(size_t)row * 512 + nt * 16 + r] = acc[mt][nt][reg] * zi;
        }
    }
}

// ============================================================================
// zw: per (b, jc): partial w[k] = sum_{j in chunk} softmax_k(leaky(f1+f2))[j,k]
// ============================================================================
__global__ __launch_bounds__(256) void zw_k(const float* __restrict__ F1,
                                            const float* __restrict__ F2,
                                            float* __restrict__ WP) {
    __shared__ float f1s[512];
    __shared__ float wpart[4][512];
    __shared__ float redm[256];
    const int b = blockIdx.x >> 4, jc = blockIdx.x & 15;
    const int tid = threadIdx.x;
    const int w = tid >> 6, lane = tid & 63;

    f1s[tid] = F1[(size_t)b * 512 + tid];
    f1s[tid + 256] = F1[(size_t)b * 512 + tid + 256];
#pragma unroll
    for (int i = 0; i < 8; ++i) wpart[w][lane + 64 * i] = 0.f;
    __syncthreads();
    redm[tid] = fmaxf(f1s[tid], f1s[tid + 256]);
    __syncthreads();
    if (tid < 64) {
        float m = fmaxf(fmaxf(redm[tid], redm[tid + 64]), fmaxf(redm[tid + 128], redm[tid + 192]));
#pragma unroll
        for (int off = 32; off >= 1; off >>= 1) m = fmaxf(m, __shfl_xor(m, off, 64));
        if (tid == 0) redm[0] = m;
    }
    __syncthreads();
    const float f1m = redm[0];

    for (int jj = 0; jj < 8; ++jj) {
        int j = jc * 32 + w * 8 + jj;
        float f2j = F2[(size_t)b * 512 + j];
        float sj = f1m + f2j;
        float mj = fmaxf(sj, ALPHA * sj);
        float pv[8];
        float z = 0.f;
#pragma unroll
        for (int i = 0; i < 8; ++i) {
            float s = f1s[lane + 64 * i] + f2j;
            s = fmaxf(s, ALPHA * s);
            float p = __expf(s - mj);
            pv[i] = p;
            z += p;
        }
#pragma unroll
        for (int off = 32; off >= 1; off >>= 1) z += __shfl_xor(z, off, 64);
        float inv = 1.f / z;
#pragma unroll
        for (int i = 0; i < 8; ++i) wpart[w][lane + 64 * i] += pv[i] * inv;
    }
    __syncthreads();
    for (int i = tid; i < 512; i += 256)
        WP[(size_t)(b * 16 + jc) * 512 + i] =
            wpart[0][i] + wpart[1][i] + wpart[2][i] + wpart[3][i];
}

// vpart: block (b, kq): v_part[d] = sum_{k in quarter} w[k] * H2[b,k,d]
__global__ __launch_bounds__(256) void vpart_k(const float* __restrict__ WP,
                                               const float* __restrict__ H2,
                                               float* __restrict__ VP) {
    __shared__ float wsL[128];
    const int b = blockIdx.x, kq = blockIdx.y;
    const int tid = threadIdx.x;
    if (tid < 128) {
        float s = 0.f;
#pragma unroll
        for (int jc = 0; jc < 16; ++jc) s += WP[(size_t)(b * 16 + jc) * 512 + kq * 128 + tid];
        wsL[tid] = s;
    }
    __syncthreads();
    const int d = tid & 127, half = tid >> 7;
    const float* h2p = H2 + ((size_t)b * 512 + kq * 128 + half * 64) * 128 + d;
    float acc = 0.f;
#pragma unroll 8
    for (int i = 0; i < 64; ++i) acc += wsL[half * 64 + i] * h2p[(size_t)i * 128];
    VP[(size_t)(b * 8 + kq * 2 + half) * 128 + d] = acc;
}

// final: v = (1/512) * sum of partials; out = normalize(v @ Wl^T + bl)
__global__ __launch_bounds__(256) void final3_k(const float* __restrict__ VP,
                                                const float* __restrict__ Wl,
                                                const float* __restrict__ bl,
                                                float* __restrict__ out) {
    __shared__ float vs[128];
    __shared__ float fo_s[128];
    __shared__ float r0;
    const int b = blockIdx.x, tid = threadIdx.x;
    if (tid < 128) {
        float v = 0.f;
#pragma unroll
        for (int q = 0; q < 8; ++q) v += VP[(size_t)(b * 8 + q) * 128 + tid];
        vs[tid] = v * (1.f / 512.f);
    }
    __syncthreads();
    if (tid < 128) {
        float fo = bl[tid];
        const float* wl = Wl + (size_t)tid * 128;
#pragma unroll 4
        for (int d = 0; d < 128; d += 4)
            fo += vs[d] * wl[d] + vs[d + 1] * wl[d + 1] + vs[d + 2] * wl[d + 2] +
                  vs[d + 3] * wl[d + 3];
        fo_s[tid] = fo;
    }
    __syncthreads();
    if (tid < 64) {
        float s = fo_s[tid] * fo_s[tid] + fo_s[tid + 64] * fo_s[tid + 64];
#pragma unroll
        for (int off = 32; off >= 1; off >>= 1) s += __shfl_xor(s, off, 64);
        if (tid == 0) r0 = s;
    }
    __syncthreads();
    float inv = 1.f / fmaxf(sqrtf(r0), 1e-12f);
    if (tid < 128) out[(size_t)b * 128 + tid] = fo_s[tid] * inv;
}

extern "C" void kernel_launch(void* const* d_in, const int* in_sizes, int n_in,
                              void* d_out, int out_size, void* d_ws, size_t ws_size,
                              hipStream_t stream) {
    const float* X = (const float*)d_in[0];
    const float* Wt = (const float*)d_in[1];
    const float* a1 = (const float*)d_in[2];
    const float* a2 = (const float*)d_in[3];
    const float* Wo = (const float*)d_in[4];
    const float* a1o = (const float*)d_in[5];
    const float* a2o = (const float*)d_in[6];
    const float* Wl = (const float*)d_in[7];
    const float* bl = (const float*)d_in[8];
    float* out = (float*)d_out;
    float* ws = (float*)d_ws;

    float* H = ws;                             // 32*512*512
    float* E1 = H + (size_t)32 * 512 * 512;    // 32*8*512
    float* E2 = E1 + (size_t)32 * 8 * 512;     // 32*8*512
    float* O = E2 + (size_t)32 * 8 * 512;      // 32*512*512
    float* H2 = O + (size_t)32 * 512 * 512;    // 32*512*128
    float* F1 = H2 + (size_t)32 * 512 * 128;   // 32*512
    float* F2 = F1 + (size_t)32 * 512;         // 32*512
    float* WP = E1;                            // overlay (E1/E2 dead): 32*16*512
    float* VP = O;                             // overlay (O dead): 32*8*128

    // GEMM1: H = X @ Wt^T, fused e1/e2
    gemm_mfma<4, false, 1><<<dim3(128, 4), 256, 0, stream>>>(
        X, Wt, H, 16384, 512, 256, a1, a2, E1, E2);
    // attention
    attn_mfma<<<512, 256, 0, stream>>>(H, E1, E2, O);
    // GEMM2: H2 = leaky(O) @ Wo^T, fused f1/f2
    gemm_mfma<2, true, 2><<<dim3(256, 1), 256, 0, stream>>>(
        O, Wo, H2, 16384, 128, 512, a1o, a2o, F1, F2);
    // output-attention softmax partials
    zw_k<<<512, 256, 0, stream>>>(F1, F2, WP);
    vpart_k<<<dim3(32, 4), 256, 0, stream>>>(WP, H2, VP);
    final3_k<<<32, 256, 0, stream>>>(VP, Wl, bl, out);
}

// Round 4
// 146.222 us; speedup vs baseline: 3.6229x; 1.3456x over previous
//
#include <hip/hip_runtime.h>
#include <hip/hip_bf16.h>
#include <math.h>

#define BB 32
#define NN 512
#define NF 256
#define NHID 64
#define NHEADS_ 8
#define NO 128
#define ALPHA 0.2f
#define ACVT 0.01f

typedef __attribute__((ext_vector_type(8))) __bf16 bf16x8;
typedef __attribute__((ext_vector_type(4))) __bf16 bf16x4;
typedef __attribute__((ext_vector_type(4))) float f32x4;

// ============================================================================
// cvt: X, Wt, Wo -> bf16 (8 elems/thread)
// X: 4194304 (524288 u), Wt: 131072 (16384 u), Wo: 65536 (8192 u) = 548864 u
// ============================================================================
__global__ __launch_bounds__(256) void cvt_k(const float* __restrict__ X,
                                             const float* __restrict__ Wt,
                                             const float* __restrict__ Wo,
                                             __bf16* __restrict__ Xb,
                                             __bf16* __restrict__ Wtb,
                                             __bf16* __restrict__ Wob) {
    int u = blockIdx.x * 256 + threadIdx.x;
    const float* src;
    __bf16* dst;
    int idx;
    if (u < 524288) { src = X; dst = Xb; idx = u; }
    else if (u < 540672) { src = Wt; dst = Wtb; idx = u - 524288; }
    else { src = Wo; dst = Wob; idx = u - 540672; }
    float4 v0 = *(const float4*)(src + (size_t)idx * 8);
    float4 v1 = *(const float4*)(src + (size_t)idx * 8 + 4);
    bf16x8 o;
    o[0] = (__bf16)v0.x; o[1] = (__bf16)v0.y; o[2] = (__bf16)v0.z; o[3] = (__bf16)v0.w;
    o[4] = (__bf16)v1.x; o[5] = (__bf16)v1.y; o[6] = (__bf16)v1.z; o[7] = (__bf16)v1.w;
    *(bf16x8*)(dst + (size_t)idx * 8) = o;
}

// ============================================================================
// GEMM1: HT[(b*8+h)*64+d][n] = sum_f Xb[b*512+n][f] * Wtb[h*64+d][f]  (bf16 out)
// fused e1/e2 (fp32). BM=128, BN=128, KC=64. 4 waves 2x2, WMT=4, NT=4.
// grid (128, 4).
// ============================================================================
__global__ __launch_bounds__(256) void gemm1_bf16(
    const __bf16* __restrict__ Xb, const __bf16* __restrict__ Wtb,
    __bf16* __restrict__ HT,
    const float* __restrict__ a1, const float* __restrict__ a2,
    float* __restrict__ E1, float* __restrict__ E2) {
    __shared__ char As[128 * 128];
    __shared__ char Bs[128 * 128];
    const int tid = threadIdx.x;
    const int w = tid >> 6, lane = tid & 63;
    const int wm = w >> 1, wn = w & 1;
    const int r = lane & 15, g = lane >> 4;
    const int m0 = blockIdx.x * 128;
    const int n0 = blockIdx.y * 128;

    f32x4 acc[4][4];
#pragma unroll
    for (int mt = 0; mt < 4; ++mt)
#pragma unroll
        for (int nt = 0; nt < 4; ++nt) {
            acc[mt][nt][0] = 0.f; acc[mt][nt][1] = 0.f;
            acc[mt][nt][2] = 0.f; acc[mt][nt][3] = 0.f;
        }

    const int sr = tid >> 3;         // 0..31
    const int sc = (tid & 7) * 16;   // byte col within 128B row

    for (int k0 = 0; k0 < 256; k0 += 64) {
        __syncthreads();
#pragma unroll
        for (int i = 0; i < 4; ++i) {
            int row = sr + i * 32;
            bf16x8 va = *(const bf16x8*)((const char*)Xb +
                                         ((size_t)(m0 + row) * 256 + k0) * 2 + sc);
            *(bf16x8*)(As + row * 128 + (sc ^ ((row & 7) << 4))) = va;
            bf16x8 vb = *(const bf16x8*)((const char*)Wtb +
                                         ((size_t)(n0 + row) * 256 + k0) * 2 + sc);
            *(bf16x8*)(Bs + row * 128 + (sc ^ ((row & 7) << 4))) = vb;
        }
        __syncthreads();
#pragma unroll
        for (int kk = 0; kk < 64; kk += 32) {
            bf16x8 af[4], bfv[4];
#pragma unroll
            for (int mt = 0; mt < 4; ++mt) {
                int row = wm * 64 + mt * 16 + r;
                af[mt] = *(const bf16x8*)(As + row * 128 +
                                          (((kk + g * 8) * 2) ^ ((row & 7) << 4)));
            }
#pragma unroll
            for (int nt = 0; nt < 4; ++nt) {
                int row = wn * 64 + nt * 16 + r;
                bfv[nt] = *(const bf16x8*)(Bs + row * 128 +
                                           (((kk + g * 8) * 2) ^ ((row & 7) << 4)));
            }
#pragma unroll
            for (int mt = 0; mt < 4; ++mt)
#pragma unroll
                for (int nt = 0; nt < 4; ++nt)
                    acc[mt][nt] = __builtin_amdgcn_mfma_f32_16x16x32_bf16(
                        af[mt], bfv[nt], acc[mt][nt], 0, 0, 0);
        }
    }

    const int h = blockIdx.y * 2 + wn;
    // ---- HT store: transposed, bf16, 8B per (mt,nt) per lane ----
#pragma unroll
    for (int mt = 0; mt < 4; ++mt) {
        int mfirst = m0 + wm * 64 + mt * 16 + g * 4;
        int b = mfirst >> 9, nn = mfirst & 511;
#pragma unroll
        for (int nt = 0; nt < 4; ++nt) {
            int d = wn * 64 + nt * 16 + r - wn * 64;  // = nt*16+r
            bf16x4 pv;
#pragma unroll
            for (int reg = 0; reg < 4; ++reg) pv[reg] = (__bf16)acc[mt][nt][reg];
            *(bf16x4*)(HT + ((size_t)(b * 8 + h) * 64 + d) * 512 + nn) = pv;
        }
    }
    // ---- e1/e2 ----
    float w1[4], w2[4];
#pragma unroll
    for (int nt = 0; nt < 4; ++nt) {
        w1[nt] = a1[h * 64 + nt * 16 + r];
        w2[nt] = a2[h * 64 + nt * 16 + r];
    }
#pragma unroll
    for (int mt = 0; mt < 4; ++mt)
#pragma unroll
        for (int reg = 0; reg < 4; ++reg) {
            float s1 = 0.f, s2 = 0.f;
#pragma unroll
            for (int nt = 0; nt < 4; ++nt) {
                s1 += acc[mt][nt][reg] * w1[nt];
                s2 += acc[mt][nt][reg] * w2[nt];
            }
#pragma unroll
            for (int off = 1; off <= 8; off <<= 1) {
                s1 += __shfl_xor(s1, off, 64);
                s2 += __shfl_xor(s2, off, 64);
            }
            if (r == 0) {
                int m = m0 + wm * 64 + mt * 16 + g * 4 + reg;
                int b = m >> 9, n = m & 511;
                E1[(size_t)(b * 8 + h) * 512 + n] = s1;
                E2[(size_t)(b * 8 + h) * 512 + n] = s2;
            }
        }
}

// ============================================================================
// attn: per (b,h,half): OL[j, h*64+d] = leaky_.01( softmax row j . H ) in bf16
// HT input bf16 [bh*64+d][k]. grid 512.
// ============================================================================
__global__ __launch_bounds__(256) void attn_mfma(const __bf16* __restrict__ HT,
                                                 const float* __restrict__ E1,
                                                 const float* __restrict__ E2,
                                                 __bf16* __restrict__ OL) {
    __shared__ char Ht[64 * 1024];   // 64 KB bf16 H^T [d][k], XOR-swizzled
    __shared__ float e1s[512];
    __shared__ float red[4][64];
    __shared__ float e1maxS;

    const int bid = blockIdx.x;
    const int bh = bid >> 1, half = bid & 1;
    const int b = bh >> 3, h = bh & 7;
    const int tid = threadIdx.x;
    const int w = tid >> 6, lane = tid & 63;
    const int r = lane & 15, g = lane >> 4;

    // ---- stage H^T: 64KB contiguous, fully coalesced 16B copies ----
    {
        const char* src = (const char*)(HT + (size_t)bh * 32768);
#pragma unroll
        for (int i = 0; i < 16; ++i) {
            int off = i * 4096 + tid * 16;
            int d = off >> 10;
            bf16x8 v = *(const bf16x8*)(src + off);
            *(bf16x8*)(Ht + (off ^ ((d & 7) << 4))) = v;
        }
    }
    for (int i = tid; i < 512; i += 256) e1s[i] = E1[(size_t)bh * 512 + i];
    __syncthreads();

    ((float*)red)[tid] = fmaxf(e1s[tid], e1s[tid + 256]);
    __syncthreads();
    if (tid < 64) {
        const float* rp = (const float*)red;
        float m = fmaxf(fmaxf(rp[tid], rp[tid + 64]), fmaxf(rp[tid + 128], rp[tid + 192]));
#pragma unroll
        for (int off = 32; off >= 1; off >>= 1) m = fmaxf(m, __shfl_xor(m, off, 64));
        if (tid == 0) e1maxS = m;
    }
    __syncthreads();
    const float e1max = e1maxS;

    float ee2[4], mm[4];
    const float* e2g = E2 + (size_t)bh * 512 + half * 256 + w * 64;
#pragma unroll
    for (int mt = 0; mt < 4; ++mt) {
        float v = e2g[mt * 16 + r];
        ee2[mt] = v;
        float s = e1max + v;
        mm[mt] = fmaxf(s, ALPHA * s);
    }

    f32x4 acc[4][4];
#pragma unroll
    for (int mt = 0; mt < 4; ++mt)
#pragma unroll
        for (int nt = 0; nt < 4; ++nt) {
            acc[mt][nt][0] = 0.f; acc[mt][nt][1] = 0.f;
            acc[mt][nt][2] = 0.f; acc[mt][nt][3] = 0.f;
        }
    float zac[4] = {0.f, 0.f, 0.f, 0.f};

    for (int c = 0; c < 16; ++c) {
        const float* ep = e1s + c * 32 + g * 8;
        float4 ea = *(const float4*)(ep);
        float4 eb = *(const float4*)(ep + 4);
        float e1c[8] = {ea.x, ea.y, ea.z, ea.w, eb.x, eb.y, eb.z, eb.w};

        bf16x8 bfr[4];
#pragma unroll
        for (int nt = 0; nt < 4; ++nt) {
            int n = nt * 16 + r;
            int off = (n << 10) + ((c * 32 + g * 8) << 1);
            off ^= (n & 7) << 4;
            bfr[nt] = *(const bf16x8*)(Ht + off);
        }
#pragma unroll
        for (int mt = 0; mt < 4; ++mt) {
            bf16x8 af;
            float zp = 0.f;
#pragma unroll
            for (int q = 0; q < 8; ++q) {
                float s = e1c[q] + ee2[mt];
                s = fmaxf(s, ALPHA * s);
                float p = __expf(s - mm[mt]);
                zp += p;
                af[q] = (__bf16)p;
            }
            zac[mt] += zp;
#pragma unroll
            for (int nt = 0; nt < 4; ++nt)
                acc[mt][nt] =
                    __builtin_amdgcn_mfma_f32_16x16x32_bf16(af, bfr[nt], acc[mt][nt], 0, 0, 0);
        }
    }

#pragma unroll
    for (int mt = 0; mt < 4; ++mt) {
        float z = zac[mt];
        z += __shfl_xor(z, 16, 64);
        z += __shfl_xor(z, 32, 64);
        if (g == 0) red[w][mt * 16 + r] = 1.f / z;
    }

    __bf16* ob = OL + ((size_t)b * 512 + half * 256 + w * 64) * 512 + h * 64;
#pragma unroll
    for (int mt = 0; mt < 4; ++mt) {
#pragma unroll
        for (int reg = 0; reg < 4; ++reg) {
            int row = mt * 16 + g * 4 + reg;
            float zi = red[w][row];
#pragma unroll
            for (int nt = 0; nt < 4; ++nt) {
                float v = acc[mt][nt][reg] * zi;
                v = fmaxf(v, ACVT * v);  // leaky 0.01 fused
                ob[(size_t)row * 512 + nt * 16 + r] = (__bf16)v;
            }
        }
    }
}

// ============================================================================
// GEMM2: H2[m][c] = sum_k OL[m][k] * Wob[c][k]  (fp32 out), fused f1/f2.
// BM=32, BN=128, KC=64. 4 waves 2x2 (wm: 16-row halves, wn: 64-col halves).
// grid 512.
// ============================================================================
__global__ __launch_bounds__(256) void gemm2_bf16(
    const __bf16* __restrict__ OL, const __bf16* __restrict__ Wob,
    float* __restrict__ H2,
    const float* __restrict__ a1o, const float* __restrict__ a2o,
    float* __restrict__ F1, float* __restrict__ F2) {
    __shared__ char As[32 * 128];
    __shared__ char Bs[128 * 128];
    __shared__ float fred[2][32][2];
    const int tid = threadIdx.x;
    const int w = tid >> 6, lane = tid & 63;
    const int wm = w >> 1, wn = w & 1;
    const int r = lane & 15, g = lane >> 4;
    const int m0 = blockIdx.x * 32;

    f32x4 acc[4];
#pragma unroll
    for (int nt = 0; nt < 4; ++nt) {
        acc[nt][0] = 0.f; acc[nt][1] = 0.f; acc[nt][2] = 0.f; acc[nt][3] = 0.f;
    }

    const int sra = tid >> 3;        // 0..31
    const int sc = (tid & 7) * 16;

    for (int k0 = 0; k0 < 512; k0 += 64) {
        __syncthreads();
        {
            bf16x8 va = *(const bf16x8*)((const char*)OL +
                                         ((size_t)(m0 + sra) * 512 + k0) * 2 + sc);
            *(bf16x8*)(As + sra * 128 + (sc ^ ((sra & 7) << 4))) = va;
        }
#pragma unroll
        for (int i = 0; i < 4; ++i) {
            int row = sra + i * 32;
            bf16x8 vb = *(const bf16x8*)((const char*)Wob +
                                         ((size_t)row * 512 + k0) * 2 + sc);
            *(bf16x8*)(Bs + row * 128 + (sc ^ ((row & 7) << 4))) = vb;
        }
        __syncthreads();
#pragma unroll
        for (int kk = 0; kk < 64; kk += 32) {
            int arow = wm * 16 + r;
            bf16x8 af = *(const bf16x8*)(As + arow * 128 +
                                         (((kk + g * 8) * 2) ^ ((arow & 7) << 4)));
            bf16x8 bfv[4];
#pragma unroll
            for (int nt = 0; nt < 4; ++nt) {
                int row = wn * 64 + nt * 16 + r;
                bfv[nt] = *(const bf16x8*)(Bs + row * 128 +
                                           (((kk + g * 8) * 2) ^ ((row & 7) << 4)));
            }
#pragma unroll
            for (int nt = 0; nt < 4; ++nt)
                acc[nt] = __builtin_amdgcn_mfma_f32_16x16x32_bf16(af, bfv[nt], acc[nt], 0, 0, 0);
        }
    }

    // ---- C store ----
#pragma unroll
    for (int reg = 0; reg < 4; ++reg) {
        int row = m0 + wm * 16 + g * 4 + reg;
#pragma unroll
        for (int nt = 0; nt < 4; ++nt)
            H2[(size_t)row * 128 + wn * 64 + nt * 16 + r] = acc[nt][reg];
    }
    // ---- f1/f2 ----
    float w1[4], w2[4];
#pragma unroll
    for (int nt = 0; nt < 4; ++nt) {
        w1[nt] = a1o[wn * 64 + nt * 16 + r];
        w2[nt] = a2o[wn * 64 + nt * 16 + r];
    }
#pragma unroll
    for (int reg = 0; reg < 4; ++reg) {
        float s1 = 0.f, s2 = 0.f;
#pragma unroll
        for (int nt = 0; nt < 4; ++nt) {
            s1 += acc[nt][reg] * w1[nt];
            s2 += acc[nt][reg] * w2[nt];
        }
#pragma unroll
        for (int off = 1; off <= 8; off <<= 1) {
            s1 += __shfl_xor(s1, off, 64);
            s2 += __shfl_xor(s2, off, 64);
        }
        if (r == 0) {
            int lr = wm * 16 + g * 4 + reg;
            fred[wn][lr][0] = s1;
            fred[wn][lr][1] = s2;
        }
    }
    __syncthreads();
    if (tid < 32) {
        int m = m0 + tid;
        int b = m >> 9, n = m & 511;
        F1[(size_t)b * 512 + n] = fred[0][tid][0] + fred[1][tid][0];
        F2[(size_t)b * 512 + n] = fred[0][tid][1] + fred[1][tid][1];
    }
}

// ============================================================================
// zw: per (b, jc): partial w[k] = sum_{j in chunk} softmax_k(leaky(f1+f2))[j,k]
// ============================================================================
__global__ __launch_bounds__(256) void zw_k(const float* __restrict__ F1,
                                            const float* __restrict__ F2,
                                            float* __restrict__ WP) {
    __shared__ float f1s[512];
    __shared__ float wpart[4][512];
    __shared__ float redm[256];
    const int b = blockIdx.x >> 4, jc = blockIdx.x & 15;
    const int tid = threadIdx.x;
    const int w = tid >> 6, lane = tid & 63;

    f1s[tid] = F1[(size_t)b * 512 + tid];
    f1s[tid + 256] = F1[(size_t)b * 512 + tid + 256];
#pragma unroll
    for (int i = 0; i < 8; ++i) wpart[w][lane + 64 * i] = 0.f;
    __syncthreads();
    redm[tid] = fmaxf(f1s[tid], f1s[tid + 256]);
    __syncthreads();
    if (tid < 64) {
        float m = fmaxf(fmaxf(redm[tid], redm[tid + 64]), fmaxf(redm[tid + 128], redm[tid + 192]));
#pragma unroll
        for (int off = 32; off >= 1; off >>= 1) m = fmaxf(m, __shfl_xor(m, off, 64));
        if (tid == 0) redm[0] = m;
    }
    __syncthreads();
    const float f1m = redm[0];

    for (int jj = 0; jj < 8; ++jj) {
        int j = jc * 32 + w * 8 + jj;
        float f2j = F2[(size_t)b * 512 + j];
        float sj = f1m + f2j;
        float mj = fmaxf(sj, ALPHA * sj);
        float pv[8];
        float z = 0.f;
#pragma unroll
        for (int i = 0; i < 8; ++i) {
            float s = f1s[lane + 64 * i] + f2j;
            s = fmaxf(s, ALPHA * s);
            float p = __expf(s - mj);
            pv[i] = p;
            z += p;
        }
#pragma unroll
        for (int off = 32; off >= 1; off >>= 1) z += __shfl_xor(z, off, 64);
        float inv = 1.f / z;
#pragma unroll
        for (int i = 0; i < 8; ++i) wpart[w][lane + 64 * i] += pv[i] * inv;
    }
    __syncthreads();
    for (int i = tid; i < 512; i += 256)
        WP[(size_t)(b * 16 + jc) * 512 + i] =
            wpart[0][i] + wpart[1][i] + wpart[2][i] + wpart[3][i];
}

// vpart: block (b, kq): v_part[d] = sum_{k in quarter} w[k] * H2[b,k,d]
__global__ __launch_bounds__(256) void vpart_k(const float* __restrict__ WP,
                                               const float* __restrict__ H2,
                                               float* __restrict__ VP) {
    __shared__ float wsL[128];
    const int b = blockIdx.x, kq = blockIdx.y;
    const int tid = threadIdx.x;
    if (tid < 128) {
        float s = 0.f;
#pragma unroll
        for (int jc = 0; jc < 16; ++jc) s += WP[(size_t)(b * 16 + jc) * 512 + kq * 128 + tid];
        wsL[tid] = s;
    }
    __syncthreads();
    const int d = tid & 127, half = tid >> 7;
    const float* h2p = H2 + ((size_t)b * 512 + kq * 128 + half * 64) * 128 + d;
    float acc = 0.f;
#pragma unroll 8
    for (int i = 0; i < 64; ++i) acc += wsL[half * 64 + i] * h2p[(size_t)i * 128];
    VP[(size_t)(b * 8 + kq * 2 + half) * 128 + d] = acc;
}

// final: v = (1/512) * sum of partials; out = normalize(v @ Wl^T + bl)
__global__ __launch_bounds__(256) void final3_k(const float* __restrict__ VP,
                                                const float* __restrict__ Wl,
                                                const float* __restrict__ bl,
                                                float* __restrict__ out) {
    __shared__ float vs[128];
    __shared__ float fo_s[128];
    __shared__ float r0;
    const int b = blockIdx.x, tid = threadIdx.x;
    if (tid < 128) {
        float v = 0.f;
#pragma unroll
        for (int q = 0; q < 8; ++q) v += VP[(size_t)(b * 8 + q) * 128 + tid];
        vs[tid] = v * (1.f / 512.f);
    }
    __syncthreads();
    if (tid < 128) {
        float fo = bl[tid];
        const float* wl = Wl + (size_t)tid * 128;
#pragma unroll 4
        for (int d = 0; d < 128; d += 4)
            fo += vs[d] * wl[d] + vs[d + 1] * wl[d + 1] + vs[d + 2] * wl[d + 2] +
                  vs[d + 3] * wl[d + 3];
        fo_s[tid] = fo;
    }
    __syncthreads();
    if (tid < 64) {
        float s = fo_s[tid] * fo_s[tid] + fo_s[tid + 64] * fo_s[tid + 64];
#pragma unroll
        for (int off = 32; off >= 1; off >>= 1) s += __shfl_xor(s, off, 64);
        if (tid == 0) r0 = s;
    }
    __syncthreads();
    float inv = 1.f / fmaxf(sqrtf(r0), 1e-12f);
    if (tid < 128) out[(size_t)b * 128 + tid] = fo_s[tid] * inv;
}

extern "C" void kernel_launch(void* const* d_in, const int* in_sizes, int n_in,
                              void* d_out, int out_size, void* d_ws, size_t ws_size,
                              hipStream_t stream) {
    const float* X = (const float*)d_in[0];
    const float* Wt = (const float*)d_in[1];
    const float* a1 = (const float*)d_in[2];
    const float* a2 = (const float*)d_in[3];
    const float* Wo = (const float*)d_in[4];
    const float* a1o = (const float*)d_in[5];
    const float* a2o = (const float*)d_in[6];
    const float* Wl = (const float*)d_in[7];
    const float* bl = (const float*)d_in[8];
    float* out = (float*)d_out;

    char* p = (char*)d_ws;
    __bf16* Xb = (__bf16*)p;  p += (size_t)4194304 * 2;   // 8 MB
    __bf16* Wtb = (__bf16*)p; p += (size_t)131072 * 2;    // 256 KB
    __bf16* Wob = (__bf16*)p; p += (size_t)65536 * 2;     // 128 KB
    __bf16* HT = (__bf16*)p;  p += (size_t)8388608 * 2;   // 16 MB
    __bf16* OL = (__bf16*)p;  p += (size_t)8388608 * 2;   // 16 MB
    float* E1 = (float*)p;    p += (size_t)131072 * 4;
    float* E2 = (float*)p;    p += (size_t)131072 * 4;
    float* H2 = (float*)p;    p += (size_t)2097152 * 4;   // 8 MB
    float* F1 = (float*)p;    p += (size_t)16384 * 4;
    float* F2 = (float*)p;    p += (size_t)16384 * 4;
    float* WP = (float*)p;    p += (size_t)262144 * 4;    // 1 MB
    float* VP = (float*)p;    p += (size_t)32768 * 4;

    cvt_k<<<2144, 256, 0, stream>>>(X, Wt, Wo, Xb, Wtb, Wob);
    gemm1_bf16<<<dim3(128, 4), 256, 0, stream>>>(Xb, Wtb, HT, a1, a2, E1, E2);
    attn_mfma<<<512, 256, 0, stream>>>(HT, E1, E2, OL);
    gemm2_bf16<<<512, 256, 0, stream>>>(OL, Wob, H2, a1o, a2o, F1, F2);
    zw_k<<<512, 256, 0, stream>>>(F1, F2, WP);
    vpart_k<<<dim3(32, 4), 256, 0, stream>>>(WP, H2, VP);
    final3_k<<<32, 256, 0, stream>>>(VP, Wl, bl, out);
}